// Round 4
// baseline (5109.486 us; speedup 1.0000x reference)
//
#include <hip/hip_runtime.h>

// LSTM: S=512, B=64, I=256, H=1024, fp32 in/out.
// Round 8: shorten the per-step serial chain.
// Round-7 (3.84ms, 7.25us/step, MfmaUtil 3.7%) remained latency-bound with FETCH_SIZE
// pinned at 334MB. Diagnosis: (a) h_seq stores are 32B partial-line writes into a
// non-resident 128MB buffer -> TCC RMW line fills (~128MB HBM fetch) on the critical
// path; (b) publish went through an LDS repack (hsh) + extra barrier; (c) publish
// store-ack RTT (s_waitcnt 0) was fully exposed before the flag store.
// This round:
//  - out stores are non-temporal (write-around, no line fill)
//  - publish direct from registers: one packed u32 sc1 store per thread; the induced
//    k-permutation {0,4,1,5,2,6,3,7} within each 8-group is folded into build_w
//  - software-pipelined x-part: x-GEMM of step s+1 issues after the publish stores;
//    in-order vmcnt retirement makes the pre-flag s_waitcnt(0) ~free
//  - hsh + one __syncthreads removed; publish/flag skipped at s=SEQ-1

#define SEQ   512
#define BATCH 64
#define ISZ   256
#define HID   1024
#define NCOL  4096            // 4 gates * HID; col = n*4 + gate (f,i,g,o)
#define KH    1024
#define KTOT  1280
#define NKS   40              // K-steps of 32
#define NKSH  32              // h-part K-steps
#define NBLK  128             // persistent blocks (32 cols = 8 n-values each)
#define NSUB  2               // two 16-col subgroups per block
#define WSUB  (NKS * 512)     // u16 elems per 16-col subgroup of weights

typedef __attribute__((ext_vector_type(8))) short bf16x8;
typedef __attribute__((ext_vector_type(4))) float f32x4;
typedef unsigned short u16;
typedef unsigned int u32;
typedef unsigned long long u64;

#define WSW_ELEMS  ((size_t)NCOL * KTOT)        // 5,242,880 bf16 = 10.5 MB
#define XB_ELEMS   ((size_t)SEQ * BATCH * ISZ)  // 8,388,608 bf16 = 16.8 MB
#define HBUF_ELEMS ((size_t)2 * BATCH * HID)    // 131,072 bf16  = 256 KB

__device__ __forceinline__ u16 f2bf(float f) {
    union { float f; unsigned int u; } c; c.f = f;
    unsigned int u = c.u;
    u += 0x7fffu + ((u >> 16) & 1u);            // RNE (inputs finite)
    return (u16)(u >> 16);
}

struct WPtrs { const float* Wh[4]; const float* Wx[4]; };

// Wsw[cg][ks][lane][j]: lane=(q<<4)|nl -> col=cg*16+nl, k=ks*32+q*8+PERM[j] (h part)
// PERM matches the register-direct h publish order: u16 pos j holds n_local
// (j>>1)+4*(j&1); x part (k>=1024) keeps identity order (xb is stored naturally).
__global__ __launch_bounds__(256) void build_w(WPtrs wp, u16* __restrict__ Wsw) {
    size_t did = (size_t)blockIdx.x * 256 + threadIdx.x;    // one 16B group each
    if (did >= WSW_ELEMS / 8) return;
    int lane = (int)(did & 63);
    size_t rest = did >> 6;
    int ks = (int)(rest % NKS);
    int cg = (int)(rest / NKS);
    int nl = lane & 15, q = lane >> 4;
    int col = cg * 16 + nl;
    int g = col & 3, n = col >> 2;
    int k0 = ks * 32 + q * 8;
    u16 tmp[8];
    if (k0 < KH) {
        const float* src = wp.Wh[g] + (size_t)n * KH + k0;
#pragma unroll
        for (int j = 0; j < 8; ++j) tmp[j] = f2bf(src[(j >> 1) + 4 * (j & 1)]);
    } else {
        const float* src = wp.Wx[g] + (size_t)n * ISZ + (k0 - KH);
#pragma unroll
        for (int j = 0; j < 8; ++j) tmp[j] = f2bf(src[j]);
    }
    *(bf16x8*)(Wsw + did * 8) = *(const bf16x8*)tmp;        // did*16 B, aligned
}

// x fp32 -> bf16 (whole sequence) + flag reset for graph replay
__global__ __launch_bounds__(256) void conv_x(const float* __restrict__ x,
                                              u16* __restrict__ xb,
                                              u32* __restrict__ flags) {
    if (blockIdx.x == 0 && threadIdx.x < NBLK)
        __hip_atomic_store(&flags[threadIdx.x], 0u, __ATOMIC_RELAXED,
                           __HIP_MEMORY_SCOPE_AGENT);
    size_t i = (size_t)blockIdx.x * 256 + threadIdx.x;      // one 8-elem group each
    float4 v0 = ((const float4*)x)[i * 2];
    float4 v1 = ((const float4*)x)[i * 2 + 1];
    u16 tmp[8] = { f2bf(v0.x), f2bf(v0.y), f2bf(v0.z), f2bf(v0.w),
                   f2bf(v1.x), f2bf(v1.y), f2bf(v1.z), f2bf(v1.w) };
    *(bf16x8*)(xb + i * 8) = *(const bf16x8*)tmp;
}

struct SeqP {
    const u16* xb;
    const float* bfh; const float* bfx;
    const float* bih; const float* bix;
    const float* bgh; const float* bgx;
    const float* boh; const float* box;
    const u16* Wsw;
    u16* hbuf;        // [2][NBLK][64 rows][8 n] bf16 ring (sc1-exchanged, compact)
    float* out;       // h_seq, h_final, c_final (fp32)
    u32* flags;       // [NBLK] per-block step counters (monotonic, reset each replay)
};

// fresh acc <- x-part GEMM for step S (K = 1024..1279); overlaps publish-ack drain
#define XPART(S) do {                                                              \
    _Pragma("unroll")                                                              \
    for (int sub_ = 0; sub_ < NSUB; ++sub_)                                        \
        _Pragma("unroll")                                                          \
        for (int jj_ = 0; jj_ < 4; ++jj_) acc[sub_][jj_] = f32x4{0.f,0.f,0.f,0.f}; \
    const u16* Xp_ = p.xb + ((size_t)(S) * BATCH + arow) * ISZ + q * 8;            \
    _Pragma("unroll")                                                              \
    for (int ks_ = 0; ks_ < 8; ++ks_) {                                            \
        bf16x8 a_  = *(const bf16x8*)(Xp_ + ks_ * 32);                             \
        bf16x8 b0_ = *(const bf16x8*)(Wlp + (size_t)(NKSH + ks_) * 512);           \
        bf16x8 b1_ = *(const bf16x8*)(Wlp + WSUB + (size_t)(NKSH + ks_) * 512);    \
        acc[0][ks_ & 3] = __builtin_amdgcn_mfma_f32_16x16x32_bf16(a_, b0_, acc[0][ks_ & 3], 0, 0, 0); \
        acc[1][ks_ & 3] = __builtin_amdgcn_mfma_f32_16x16x32_bf16(a_, b1_, acc[1][ks_ & 3], 0, 0, 0); \
    }                                                                              \
} while (0)

__global__ __launch_bounds__(256, 1) void lstm_seq(SeqP p) {
    __shared__ __attribute__((aligned(16))) u16   Wl[NSUB * WSUB];   // 80 KB B-frags
    __shared__ __attribute__((aligned(16))) float Gsh[NSUB][4][16][20]; // 10 KB D exch

    const int t    = threadIdx.x;
    const int lane = t & 63;
    const int w    = t >> 6;             // wave: batch rows w*16..+16
    const int cg2  = blockIdx.x;         // block: cols cg2*32..+32 (n = cg2*8..+8)
    const int ml   = lane & 15;          // A row / D col index
    const int q    = lane >> 4;          // quad
    const int arow = w * 16 + ml;        // global batch row for A-frags

    // stage this block's weights to LDS once (5120 float4s, 20 per thread)
    {
        const float4* src = (const float4*)(p.Wsw + (size_t)cg2 * (NSUB * WSUB));
        float4* dst = (float4*)Wl;
#pragma unroll
        for (int i = 0; i < 20; ++i) dst[t + 256 * i] = src[t + 256 * i];
    }

    // epilogue mapping: thread -> b = w*16 + lane>>2, n[sub] = cg2*8 + sub*4 + lane&3
    const int row2 = lane >> 2;
    const int hl   = lane & 3;
    const int bb   = w * 16 + row2;
    float Bf[NSUB], Bi[NSUB], Bg[NSUB], Bo[NSUB], c[NSUB];
#pragma unroll
    for (int sub = 0; sub < NSUB; ++sub) {
        int nn = cg2 * 8 + sub * 4 + hl;
        Bf[sub] = p.bfh[nn] + p.bfx[nn];
        Bi[sub] = p.bih[nn] + p.bix[nn];
        Bg[sub] = p.bgh[nn] + p.bgx[nn];
        Bo[sub] = p.boh[nn] + p.box[nn];
        c[sub]  = 0.f;
    }

    const u16* Wlp = Wl + lane * 8;       // + sub*WSUB + ks*512 elems
    union AFrag { u64 d[2]; bf16x8 v; };

    __syncthreads();                      // Wl ready

    f32x4 acc[NSUB][4];
    XPART(0);                             // prologue: x-part of step 0

    for (int s = 0; s < SEQ; ++s) {
        if (s > 0) {
            // wait: every block has published h(s-1). Wave 0 polls all 128 flags
            // (one u64 load per lane); syncthreads broadcasts arrival.
            if (w == 0) {
                const u64* f2 = (const u64*)p.flags + lane;   // flags[2*lane..+2]
                for (;;) {
                    u64 v = __hip_atomic_load(f2, __ATOMIC_RELAXED,
                                              __HIP_MEMORY_SCOPE_AGENT);
                    int ok = ((u32)v >= (u32)s) && ((u32)(v >> 32) >= (u32)s);
                    if (__all(ok)) break;
                    __builtin_amdgcn_s_sleep(2);
                }
            }
            __syncthreads();
            __builtin_amdgcn_fence(__ATOMIC_ACQUIRE, "workgroup"); // compile-order only

            // h-part: K = 0..1023. k-group (ks,q) -> producer blk = ks*4+q;
            // A-frag = hrd[blk][arow][0..8] : 16 lanes read 256B contiguous.
            const u64* hrd = (const u64*)(p.hbuf + (size_t)(s & 1) * (BATCH * HID));
            const u64* Ap = hrd + (size_t)arow * 2;   // + blk*128 + d
#pragma unroll 8
            for (int ks = 0; ks < NKSH; ++ks) {
                const u64* Ab = Ap + (size_t)(ks * 4 + q) * 128;
                AFrag a;
                a.d[0] = __hip_atomic_load(Ab,     __ATOMIC_RELAXED, __HIP_MEMORY_SCOPE_AGENT);
                a.d[1] = __hip_atomic_load(Ab + 1, __ATOMIC_RELAXED, __HIP_MEMORY_SCOPE_AGENT);
                bf16x8 b0 = *(const bf16x8*)(Wlp + (size_t)ks * 512);
                bf16x8 b1 = *(const bf16x8*)(Wlp + WSUB + (size_t)ks * 512);
                acc[0][ks & 3] = __builtin_amdgcn_mfma_f32_16x16x32_bf16(a.v, b0, acc[0][ks & 3], 0, 0, 0);
                acc[1][ks & 3] = __builtin_amdgcn_mfma_f32_16x16x32_bf16(a.v, b1, acc[1][ks & 3], 0, 0, 0);
            }
        }

        // D layout: col = lane&15, row = q*4+r  (m89-verified); intra-wave exchange
#pragma unroll
        for (int sub = 0; sub < NSUB; ++sub) {
            f32x4 av = (acc[sub][0] + acc[sub][1]) + (acc[sub][2] + acc[sub][3]);
#pragma unroll
            for (int r = 0; r < 4; ++r) Gsh[sub][w][q * 4 + r][ml] = av[r];
        }
        __syncthreads();   // also orders Gsh reuse across steps

        float hv[NSUB];
#pragma unroll
        for (int sub = 0; sub < NSUB; ++sub) {
            float4 gv = *(const float4*)&Gsh[sub][w][row2][hl * 4]; // f,i,g,o preacts
            float fg = 1.f / (1.f + __expf(-(gv.x + Bf[sub])));
            float ig = 1.f / (1.f + __expf(-(gv.y + Bi[sub])));
            float gg = 1.f - 2.f / (1.f + __expf(2.f * (gv.z + Bg[sub])));
            float og = 1.f / (1.f + __expf(-(gv.w + Bo[sub])));
            c[sub] = c[sub] * fg + ig * gg;
            hv[sub] = (1.f - 2.f / (1.f + __expf(2.f * c[sub]))) * og;
        }

        if (s < SEQ - 1) {
            // publish h(s) straight from registers: one packed u32 sc1 store/thread.
            // Row's u16 order = PERM in build_w; region [blk][64 rows][8 n] compact.
            u32* hwr32 = (u32*)p.hbuf + (size_t)((s + 1) & 1) * (BATCH * HID / 2);
            u32 pk = (u32)f2bf(hv[0]) | ((u32)f2bf(hv[1]) << 16);
            __hip_atomic_store(hwr32 + (size_t)cg2 * 256 + bb * 4 + hl, pk,
                               __ATOMIC_RELAXED, __HIP_MEMORY_SCOPE_AGENT);
        }

        // h_seq: non-temporal (write-around -> no partial-line RMW fetch)
#pragma unroll
        for (int sub = 0; sub < NSUB; ++sub) {
            int nn = cg2 * 8 + sub * 4 + hl;
            __builtin_nontemporal_store(hv[sub],
                &p.out[(size_t)s * (BATCH * HID) + (size_t)bb * HID + nn]);
            if (s == SEQ - 1) {
                __builtin_nontemporal_store(hv[sub],
                    &p.out[(size_t)SEQ * (BATCH * HID) + (size_t)bb * HID + nn]);
                __builtin_nontemporal_store(c[sub],
                    &p.out[(size_t)SEQ * (BATCH * HID) + (BATCH * HID) + (size_t)bb * HID + nn]);
            }
        }

        if (s < SEQ - 1) {
            // x-part of step s+1: its load-waits drain the older publish stores
            // (in-order vmcnt), so the waitcnt(0) before the flag is ~free.
            XPART(s + 1);
            __builtin_amdgcn_fence(__ATOMIC_RELEASE, "workgroup"); // compile-order only
            __builtin_amdgcn_s_waitcnt(0);   // publish stores ack'd at coherence point
            __syncthreads();
            if (t == 0)
                __hip_atomic_store(&p.flags[cg2], (u32)(s + 1), __ATOMIC_RELAXED,
                                   __HIP_MEMORY_SCOPE_AGENT);
        }
    }
}

extern "C" void kernel_launch(void* const* d_in, const int* in_sizes, int n_in,
                              void* d_out, int out_size, void* d_ws, size_t ws_size,
                              hipStream_t stream) {
    WPtrs wp;
    wp.Wx[0] = (const float*)d_in[1];  wp.Wx[1] = (const float*)d_in[3];
    wp.Wx[2] = (const float*)d_in[5];  wp.Wx[3] = (const float*)d_in[7];
    wp.Wh[0] = (const float*)d_in[9];  wp.Wh[1] = (const float*)d_in[11];
    wp.Wh[2] = (const float*)d_in[13]; wp.Wh[3] = (const float*)d_in[15];

    u16* Wsw  = (u16*)d_ws;                                 // 10.5 MB
    u16* xb   = Wsw + WSW_ELEMS;                            // 16.8 MB
    u16* hbuf = xb + XB_ELEMS;                              // 256 KB
    u32* flags = (u32*)(hbuf + HBUF_ELEMS);                 // 512 B

    SeqP p;
    p.xb   = xb;
    p.bfx  = (const float*)d_in[2];   p.bix  = (const float*)d_in[4];
    p.bgx  = (const float*)d_in[6];   p.box  = (const float*)d_in[8];
    p.bfh  = (const float*)d_in[10];  p.bih  = (const float*)d_in[12];
    p.bgh  = (const float*)d_in[14];  p.boh  = (const float*)d_in[16];
    p.Wsw  = Wsw;
    p.hbuf = hbuf;
    p.out  = (float*)d_out;
    p.flags = flags;

    build_w<<<dim3(2560), 256, 0, stream>>>(wp, Wsw);
    conv_x<<<dim3(4096), 256, 0, stream>>>((const float*)d_in[0], xb, flags);
    lstm_seq<<<dim3(NBLK), 256, 0, stream>>>(p);
}